// Round 1
// baseline (131.405 us; speedup 1.0000x reference)
//
#include <hip/hip_runtime.h>

#define B   64
#define T   2000
#define DQ  1024
#define DM  512
#define D   128
#define F   32
#define KK  31
#define WIN 7
#define NCH 32
#define CH  63   // ceil(T/NCH)

// ws layout (floats):
//   pq      : [B][D]          @ 0       (8192)
//   wa      : [B][8]          @ 8192    (512)
//   meta    : [B][4] (ints)   @ 8704    (256)
//   part    : [B][NCH][DM]    @ 9216    (1048576)   [or ctx [B][DM] in atomic mode]
#define PQ_OFF   0
#define WA_OFF   8192
#define META_OFF 8704
#define PART_OFF 9216

// out layout (floats):
//   attention  [B][D]  @ 0
//   alignments [B][T]  @ 8192
//   next_state [B][T]  @ 8192 + B*T
//   max_att    [B]     @ 8192 + 2*B*T   (as float)
#define OUT_ALIGN 8192
#define OUT_NEXT  (8192 + B*T)
#define OUT_ARG   (8192 + 2*B*T)

__global__ void k1_pq(const float* __restrict__ q, const float* __restrict__ Wq,
                      float* __restrict__ pq) {
    int b = blockIdx.x, d = threadIdx.x;           // 128 threads
    __shared__ float qs[DQ];
    for (int k = d; k < DQ; k += 128) qs[k] = q[b * DQ + k];
    __syncthreads();
    float acc = 0.f;
    for (int k = 0; k < DQ; ++k) acc += qs[k] * Wq[k * D + d];
    pq[b * D + d] = acc;
}

__global__ void k2_energy(const float* __restrict__ mem, const float* __restrict__ pa,
                          const int* __restrict__ pm, const int* __restrict__ ml,
                          const float* __restrict__ Wm, const float* __restrict__ ck,
                          const float* __restrict__ cb, const float* __restrict__ Wloc,
                          const float* __restrict__ sv, const float* __restrict__ sb,
                          const float* __restrict__ pq,
                          float* __restrict__ wa, int* __restrict__ meta) {
    int b = blockIdx.x;
    int tid = threadIdx.x;                          // 128 threads
    int p = pm[b], L = ml[b];
    int wstart = p, wlen = 0;
    if (p < L) { int we = p + WIN; if (we > L) we = L; wlen = we - p; }

    __shared__ float mrow[DM];
    __shared__ float fsh[F];
    __shared__ float wsum2[2];
    __shared__ float esh[WIN];

    for (int i = 0; i < wlen; ++i) {
        int t = wstart + i;
        const float* mr = mem + ((size_t)b * T + t) * DM;
        for (int m = tid; m < DM; m += 128) mrow[m] = mr[m];
        if (tid < F) {
            float acc = cb[tid];
            for (int k = 0; k < KK; ++k) {
                int tt = t + k - 15;
                float x = (tt >= 0 && tt < T) ? pa[(size_t)b * T + tt] : 0.f;
                acc += x * ck[k * F + tid];
            }
            fsh[tid] = acc;
        }
        __syncthreads();
        float val = 0.f;
        for (int m = 0; m < DM; ++m) val += mrow[m] * Wm[m * D + tid];
        float pl = 0.f;
        for (int ff = 0; ff < F; ++ff) pl += fsh[ff] * Wloc[ff * D + tid];
        float x = sv[tid] * tanhf(val + pq[b * D + tid] + pl + sb[tid]);
        for (int o = 32; o > 0; o >>= 1) x += __shfl_down(x, o);
        if ((tid & 63) == 0) wsum2[tid >> 6] = x;
        __syncthreads();
        if (tid == 0) esh[i] = wsum2[0] + wsum2[1];
        __syncthreads();
    }

    if (tid == 0) {
        float a[WIN];
        int best = 0;
        if (wlen > 0) {
            float mx = esh[0];
            for (int i = 1; i < wlen; ++i) if (esh[i] > mx) mx = esh[i];
            float s = 0.f;
            for (int i = 0; i < wlen; ++i) { a[i] = expf(esh[i] - mx); s += a[i]; }
            float inv = 1.f / s;
            float ab = -1.f;
            for (int i = 0; i < wlen; ++i) {
                a[i] *= inv;
                if (a[i] > ab) { ab = a[i]; best = i; }
            }
        }
        for (int i = 0; i < 8; ++i) wa[b * 8 + i] = (i < wlen) ? a[i] : 0.f;
        meta[b * 4 + 0] = wstart;
        meta[b * 4 + 1] = wlen;
        meta[b * 4 + 2] = (wlen > 0) ? (wstart + best) : 0;
        meta[b * 4 + 3] = 0;
    }
}

__global__ void k3_outputs(const float* __restrict__ pa, const int* __restrict__ pm,
                           const int* __restrict__ ml, const float* __restrict__ wa,
                           const int* __restrict__ meta, float* __restrict__ out) {
    int idx = blockIdx.x * 256 + threadIdx.x;
    if (idx >= B * T) return;
    int b = idx / T, t = idx - b * T;
    int p = pm[b], L = ml[b];
    float a;
    if (p >= L) {
        a = 1.f / (float)T;
    } else {
        int ws_ = meta[b * 4], wl = meta[b * 4 + 1];
        a = (t >= ws_ && t < ws_ + wl) ? wa[b * 8 + (t - ws_)] : 0.f;
    }
    out[OUT_ALIGN + idx] = a;
    out[OUT_NEXT + idx] = pa[idx] + a;
    if (t == 0) out[OUT_ARG + b] = (float)meta[b * 4 + 2];
}

__global__ void k_zero_ctx(float* __restrict__ ctx) {
    int idx = blockIdx.x * 256 + threadIdx.x;
    if (idx < B * DM) ctx[idx] = 0.f;
}

// mode 0: write partial[b][c][:] ; mode 1: atomicAdd into ctx[b][:]
__global__ void k4_ctx(const float* __restrict__ mem, const int* __restrict__ pm,
                       const int* __restrict__ ml, const float* __restrict__ wa,
                       const int* __restrict__ meta, float* __restrict__ dst, int mode) {
    int b = blockIdx.x / NCH, c = blockIdx.x % NCH;
    int t0 = c * CH, t1 = t0 + CH;
    if (t1 > T) t1 = T;
    int tid = threadIdx.x;                          // 256 threads
    int p = pm[b], L = ml[b];
    bool deg = (p >= L);
    float acc0 = 0.f, acc1 = 0.f;
    if (deg) {
        for (int t = t0; t < t1; ++t) {
            const float* mr = mem + ((size_t)b * T + t) * DM;
            acc0 += mr[tid];
            acc1 += mr[tid + 256];
        }
        acc0 *= 1.f / (float)T;
        acc1 *= 1.f / (float)T;
    } else {
        int ws_ = meta[b * 4], wl = meta[b * 4 + 1];
        int s = t0 > ws_ ? t0 : ws_;
        int e = (t1 < ws_ + wl) ? t1 : ws_ + wl;
        for (int t = s; t < e; ++t) {
            float w = wa[b * 8 + (t - ws_)];
            const float* mr = mem + ((size_t)b * T + t) * DM;
            acc0 += w * mr[tid];
            acc1 += w * mr[tid + 256];
        }
    }
    if (mode == 0) {
        float* pp = dst + ((size_t)b * NCH + c) * DM;
        pp[tid] = acc0;
        pp[tid + 256] = acc1;
    } else {
        if (acc0 != 0.f) atomicAdd(&dst[b * DM + tid], acc0);
        if (acc1 != 0.f) atomicAdd(&dst[b * DM + tid + 256], acc1);
    }
}

// nch: 32 (partials) or 1 (pre-summed ctx)
__global__ void k5_attention(const float* __restrict__ part, const float* __restrict__ Wm,
                             float* __restrict__ out, int nch) {
    int b = blockIdx.x, tid = threadIdx.x;          // 512 threads
    __shared__ float ctx[DM];
    float s = 0.f;
    for (int c = 0; c < nch; ++c) s += part[((size_t)b * nch + c) * DM + tid];
    ctx[tid] = s;
    __syncthreads();
    if (tid < D) {
        float acc = 0.f;
        for (int m = 0; m < DM; ++m) acc += ctx[m] * Wm[m * D + tid];
        out[b * D + tid] = acc;
    }
}

extern "C" void kernel_launch(void* const* d_in, const int* in_sizes, int n_in,
                              void* d_out, int out_size, void* d_ws, size_t ws_size,
                              hipStream_t stream) {
    const float* query = (const float*)d_in[0];
    const float* memory = (const float*)d_in[1];
    const float* prev_align = (const float*)d_in[2];
    const int* prev_max = (const int*)d_in[3];
    const int* mem_len = (const int*)d_in[4];
    const float* Wq = (const float*)d_in[5];
    const float* Wm = (const float*)d_in[6];
    const float* ck = (const float*)d_in[7];
    const float* cb = (const float*)d_in[8];
    const float* Wloc = (const float*)d_in[9];
    const float* sv = (const float*)d_in[10];
    const float* sb = (const float*)d_in[11];
    float* out = (float*)d_out;

    float* wsf = (float*)d_ws;
    float* pq = wsf + PQ_OFF;
    float* wa = wsf + WA_OFF;
    int* meta = (int*)(wsf + META_OFF);
    float* part = wsf + PART_OFF;

    size_t need_partials = (size_t)(PART_OFF + B * NCH * DM) * 4;
    bool use_partials = (ws_size >= need_partials);

    k1_pq<<<B, 128, 0, stream>>>(query, Wq, pq);
    k2_energy<<<B, 128, 0, stream>>>(memory, prev_align, prev_max, mem_len, Wm, ck, cb,
                                     Wloc, sv, sb, pq, wa, meta);
    k3_outputs<<<(B * T + 255) / 256, 256, 0, stream>>>(prev_align, prev_max, mem_len,
                                                        wa, meta, out);
    if (use_partials) {
        k4_ctx<<<B * NCH, 256, 0, stream>>>(memory, prev_max, mem_len, wa, meta, part, 0);
        k5_attention<<<B, 512, 0, stream>>>(part, Wm, out, NCH);
    } else {
        k_zero_ctx<<<(B * DM + 255) / 256, 256, 0, stream>>>(part);
        k4_ctx<<<B * NCH, 256, 0, stream>>>(memory, prev_max, mem_len, wa, meta, part, 1);
        k5_attention<<<B, 512, 0, stream>>>(part, Wm, out, 1);
    }
}

// Round 2
// 84.654 us; speedup vs baseline: 1.5523x; 1.5523x over previous
//
#include <hip/hip_runtime.h>

#define B   64
#define T   2000
#define DQ  1024
#define DM  512
#define D   128
#define F   32
#define KK  31
#define WIN 7
#define NCH 32
#define CH  63   // ceil(T/NCH)

// ws layout (floats):
//   wa   : [B][8]        @ 0     (512)
//   meta : [B][4] (ints) @ 512   (256)
//   part : [B][NCH][DM]  @ 768   (1048576)  [or ctx [B][DM] in atomic mode]
#define WA_OFF   0
#define META_OFF 512
#define PART_OFF 768

// out layout (floats):
//   attention  [B][D]  @ 0
//   alignments [B][T]  @ 8192
//   next_state [B][T]  @ 8192 + B*T
//   max_att    [B]     @ 8192 + 2*B*T   (as float)
#define OUT_ALIGN 8192
#define OUT_NEXT  (8192 + B*T)
#define OUT_ARG   (8192 + 2*B*T)

// ---------------- KA: pq + window energies + softmax (one block per batch) ---------
__global__ void __launch_bounds__(512)
kA(const float* __restrict__ q, const float* __restrict__ mem,
   const float* __restrict__ pa, const int* __restrict__ pm, const int* __restrict__ ml,
   const float* __restrict__ Wq, const float* __restrict__ Wm,
   const float* __restrict__ ck, const float* __restrict__ cb,
   const float* __restrict__ Wloc, const float* __restrict__ sv,
   const float* __restrict__ sb, float* __restrict__ wa, int* __restrict__ meta) {
    int b = blockIdx.x;
    int tid = threadIdx.x;
    int lane = tid & 63;
    int wave = tid >> 6;

    __shared__ float qs[DQ];
    __shared__ float pqpart[4][D];
    __shared__ float pqs[D];          // pq + score_b
    __shared__ float mrow[WIN][DM];
    __shared__ float fsh[WIN][F];
    __shared__ float esh[WIN];

    int p = pm[b], L = ml[b];
    int wstart = p, wlen = 0;
    if (p < L) { int we = p + WIN; if (we > L) we = L; wlen = we - p; }

    // stage q row (1024 floats)
    qs[tid] = q[(size_t)b * DQ + tid];
    qs[tid + 512] = q[(size_t)b * DQ + tid + 512];
    __syncthreads();

    // pq partials: thread = (j=tid>>7 in [0,4), d=tid&127), each sums 256 of 1024 k
    {
        int d = tid & 127, j = tid >> 7;
        int k0 = j * 256;
        float acc = 0.f;
        for (int k = 0; k < 256; ++k) acc += qs[k0 + k] * Wq[(size_t)(k0 + k) * D + d];
        pqpart[j][d] = acc;
    }

    // stage memory window rows (wlen * 512 floats)
    for (int e = tid; e < wlen * DM; e += 512) {
        int i = e >> 9, m = e & 511;
        mrow[i][m] = mem[((size_t)b * T + wstart + i) * DM + m];
    }

    // conv location features: thread (i=tid>>5, f=tid&31) for tid < 7*32
    if (tid < WIN * F) {
        int i = tid >> 5, f = tid & 31;
        if (i < wlen) {
            int t = wstart + i;
            float acc = cb[f];
            for (int k = 0; k < KK; ++k) {
                int tt = t + k - 15;
                float x = (tt >= 0 && tt < T) ? pa[(size_t)b * T + tt] : 0.f;
                acc += x * ck[k * F + f];
            }
            fsh[i][f] = acc;
        }
    }
    __syncthreads();

    if (tid < D)
        pqs[tid] = pqpart[0][tid] + pqpart[1][tid] + pqpart[2][tid] + pqpart[3][tid] + sb[tid];
    __syncthreads();

    // energies: wave i computes window position i; lane holds cols c0=2*lane, c1=c0+1
    if (wave < wlen) {
        int i = wave;
        const float2* Wm2 = (const float2*)Wm;
        float v0 = 0.f, v1 = 0.f, v2 = 0.f, v3 = 0.f;
        for (int m = 0; m < DM; m += 2) {
            float a0 = mrow[i][m], a1 = mrow[i][m + 1];
            float2 w0 = Wm2[(size_t)m * 64 + lane];
            float2 w1 = Wm2[(size_t)(m + 1) * 64 + lane];
            v0 += a0 * w0.x; v1 += a0 * w0.y;
            v2 += a1 * w1.x; v3 += a1 * w1.y;
        }
        const float2* Wl2 = (const float2*)Wloc;
        float p0 = 0.f, p1 = 0.f;
        for (int f = 0; f < F; ++f) {
            float fv = fsh[i][f];
            float2 w = Wl2[f * 64 + lane];
            p0 += fv * w.x; p1 += fv * w.y;
        }
        int c0 = 2 * lane, c1 = c0 + 1;
        float x = sv[c0] * tanhf(v0 + v2 + pqs[c0] + p0)
                + sv[c1] * tanhf(v1 + v3 + pqs[c1] + p1);
        for (int o = 32; o > 0; o >>= 1) x += __shfl_xor(x, o);
        if (lane == 0) esh[i] = x;
    }
    __syncthreads();

    if (tid == 0) {
        float a[WIN];
        int best = 0;
        if (wlen > 0) {
            float mx = esh[0];
            for (int i = 1; i < wlen; ++i) if (esh[i] > mx) mx = esh[i];
            float s = 0.f;
            for (int i = 0; i < wlen; ++i) { a[i] = expf(esh[i] - mx); s += a[i]; }
            float inv = 1.f / s;
            float ab = -1.f;
            for (int i = 0; i < wlen; ++i) {
                a[i] *= inv;
                if (a[i] > ab) { ab = a[i]; best = i; }
            }
        }
        for (int i = 0; i < 8; ++i) wa[b * 8 + i] = (i < wlen) ? a[i] : 0.f;
        meta[b * 4 + 0] = wstart;
        meta[b * 4 + 1] = wlen;
        meta[b * 4 + 2] = (wlen > 0) ? (wstart + best) : 0;
        meta[b * 4 + 3] = 0;
    }
}

// ---------------- KB: alignments/next_state/argmax writes + ctx partials ----------
// mode 0: write partial[b][c][:] ; mode 1: atomicAdd into ctx[b][:]
__global__ void __launch_bounds__(256)
kB(const float* __restrict__ mem, const float* __restrict__ pa,
   const int* __restrict__ pm, const int* __restrict__ ml,
   const float* __restrict__ wa, const int* __restrict__ meta,
   float* __restrict__ dst, float* __restrict__ out, int mode) {
    int b = blockIdx.x / NCH, c = blockIdx.x % NCH;
    int tid = threadIdx.x;                       // 256
    int t0 = c * CH, t1 = t0 + CH;
    if (t1 > T) t1 = T;
    int p = pm[b], L = ml[b];
    bool deg = (p >= L);
    int ws_ = meta[b * 4], wl = meta[b * 4 + 1];

    // outputs for this chunk
    int t = t0 + tid;
    if (tid < CH && t < T) {
        float a;
        if (deg) a = 1.f / (float)T;
        else     a = (t >= ws_ && t < ws_ + wl) ? wa[b * 8 + (t - ws_)] : 0.f;
        out[OUT_ALIGN + b * T + t] = a;
        out[OUT_NEXT + b * T + t] = pa[(size_t)b * T + t] + a;
    }
    if (c == 0 && tid == 0) out[OUT_ARG + b] = (float)meta[b * 4 + 2];

    // ctx partials
    float acc0 = 0.f, acc1 = 0.f;
    if (deg) {
        for (int tt = t0; tt < t1; ++tt) {
            const float* mr = mem + ((size_t)b * T + tt) * DM;
            acc0 += mr[tid];
            acc1 += mr[tid + 256];
        }
        acc0 *= 1.f / (float)T;
        acc1 *= 1.f / (float)T;
    } else {
        int s = t0 > ws_ ? t0 : ws_;
        int e = (t1 < ws_ + wl) ? t1 : ws_ + wl;
        for (int tt = s; tt < e; ++tt) {
            float w = wa[b * 8 + (tt - ws_)];
            const float* mr = mem + ((size_t)b * T + tt) * DM;
            acc0 += w * mr[tid];
            acc1 += w * mr[tid + 256];
        }
    }
    if (mode == 0) {
        float* pp = dst + ((size_t)b * NCH + c) * DM;
        pp[tid] = acc0;
        pp[tid + 256] = acc1;
    } else {
        if (acc0 != 0.f) atomicAdd(&dst[b * DM + tid], acc0);
        if (acc1 != 0.f) atomicAdd(&dst[b * DM + tid + 256], acc1);
    }
}

__global__ void k_zero_ctx(float* __restrict__ ctx) {
    int idx = blockIdx.x * 256 + threadIdx.x;
    if (idx < B * DM) ctx[idx] = 0.f;
}

// ---------------- KC: attention = ctx @ Wm ----------------------------------------
__global__ void __launch_bounds__(512)
kC(const float* __restrict__ part, const float* __restrict__ Wm,
   float* __restrict__ out, int nch) {
    int b = blockIdx.x, tid = threadIdx.x;       // 512
    __shared__ float ctx[DM];
    float s = 0.f;
    for (int c = 0; c < nch; ++c) s += part[((size_t)b * nch + c) * DM + tid];
    ctx[tid] = s;
    __syncthreads();
    if (tid < D) {
        float acc = 0.f;
        for (int m = 0; m < DM; ++m) acc += ctx[m] * Wm[(size_t)m * D + tid];
        out[b * D + tid] = acc;
    }
}

extern "C" void kernel_launch(void* const* d_in, const int* in_sizes, int n_in,
                              void* d_out, int out_size, void* d_ws, size_t ws_size,
                              hipStream_t stream) {
    const float* query = (const float*)d_in[0];
    const float* memory = (const float*)d_in[1];
    const float* prev_align = (const float*)d_in[2];
    const int* prev_max = (const int*)d_in[3];
    const int* mem_len = (const int*)d_in[4];
    const float* Wq = (const float*)d_in[5];
    const float* Wm = (const float*)d_in[6];
    const float* ck = (const float*)d_in[7];
    const float* cb = (const float*)d_in[8];
    const float* Wloc = (const float*)d_in[9];
    const float* sv = (const float*)d_in[10];
    const float* sb = (const float*)d_in[11];
    float* out = (float*)d_out;

    float* wsf = (float*)d_ws;
    float* wa = wsf + WA_OFF;
    int* meta = (int*)(wsf + META_OFF);
    float* part = wsf + PART_OFF;

    size_t need_partials = (size_t)(PART_OFF + B * NCH * DM) * 4;
    bool use_partials = (ws_size >= need_partials);

    kA<<<B, 512, 0, stream>>>(query, memory, prev_align, prev_max, mem_len,
                              Wq, Wm, ck, cb, Wloc, sv, sb, wa, meta);
    if (use_partials) {
        kB<<<B * NCH, 256, 0, stream>>>(memory, prev_align, prev_max, mem_len,
                                        wa, meta, part, out, 0);
        kC<<<B, 512, 0, stream>>>(part, Wm, out, NCH);
    } else {
        k_zero_ctx<<<(B * DM + 255) / 256, 256, 0, stream>>>(part);
        kB<<<B * NCH, 256, 0, stream>>>(memory, prev_align, prev_max, mem_len,
                                        wa, meta, part, out, 1);
        kC<<<B, 512, 0, stream>>>(part, Wm, out, 1);
    }
}

// Round 3
// 41.922 us; speedup vs baseline: 3.1345x; 2.0193x over previous
//
#include <hip/hip_runtime.h>

#define B   64
#define T   2000
#define DQ  1024
#define DM  512
#define D   128
#define F   32
#define KK  31
#define WIN 7
#define NCH 32
#define CH  63    // ceil(T/NCH)
#define NB2 8     // output-writer blocks per batch in K2
#define NTB 250   // T / NB2

// ws layout (floats):
//   wa   : [B][8]         @ 0      (512)
//   meta : [B][4] (ints)  @ 512    (256)
//   ctx  : [B][DM]        @ 768    (32768)
//   part : [B][NCH][DM]   @ 33536  (1048576)
#define WA_OFF   0
#define META_OFF 512
#define CTX_OFF  768
#define PART_OFF 33536

// out layout (floats):
//   attention  [B][D]  @ 0
//   alignments [B][T]  @ 8192
//   next_state [B][T]  @ 8192 + B*T
//   max_att    [B]     @ 8192 + 2*B*T   (as float)
#define OUT_ALIGN 8192
#define OUT_NEXT  (8192 + B*T)
#define OUT_ARG   (8192 + 2*B*T)

// ---------------- K1: blocks [0,B): energies+softmax+window-ctx -------------------
//                     blocks [B, B+B*NCH): degenerate colsum partials
// mode 0: partials to part[][];  mode 1: atomicAdd into ctx[] (pre-zeroed)
__global__ void __launch_bounds__(512)
K1(const float* __restrict__ q, const float* __restrict__ mem,
   const float* __restrict__ pa, const int* __restrict__ pm, const int* __restrict__ ml,
   const float* __restrict__ Wq, const float* __restrict__ Wm,
   const float* __restrict__ ck, const float* __restrict__ cb,
   const float* __restrict__ Wloc, const float* __restrict__ sv,
   const float* __restrict__ sb, float* __restrict__ wa, int* __restrict__ meta,
   float* __restrict__ ctx, float* __restrict__ part, int mode) {
    int blk = blockIdx.x;
    int tid = threadIdx.x;

    if (blk >= B) {
        // ---------- degenerate colsum partial ----------
        int idx = blk - B;
        int b = idx / NCH, c = idx % NCH;
        if (pm[b] < ml[b]) return;                 // non-degenerate: nothing to do
        int t0 = c * CH, t1 = t0 + CH;
        if (t1 > T) t1 = T;
        float acc = 0.f;
        const float* mp = mem + (size_t)b * T * DM + tid;
        for (int t = t0; t < t1; ++t) acc += mp[(size_t)t * DM];
        acc *= (1.f / (float)T);
        if (mode == 0) part[((size_t)b * NCH + c) * DM + tid] = acc;
        else if (acc != 0.f) atomicAdd(&ctx[b * DM + tid], acc);
        return;
    }

    // ---------- energy / softmax / window-ctx for batch b ----------
    int b = blk;
    int lane = tid & 63;
    int wave = tid >> 6;

    __shared__ float qs[DQ];
    __shared__ float pqpart[4][D];
    __shared__ float pqs[D];
    __shared__ float mrow[WIN][DM];
    __shared__ float fsh[WIN][F];
    __shared__ float2 pacc2[WIN][8][64];
    __shared__ float esh[WIN];
    __shared__ float ash[8];

    int p = pm[b], L = ml[b];
    int wstart = p, wlen = 0;
    if (p < L) { int we = p + WIN; if (we > L) we = L; wlen = we - p; }

    // stage q row
    qs[tid] = q[(size_t)b * DQ + tid];
    qs[tid + 512] = q[(size_t)b * DQ + tid + 512];

    // stage window memory rows (zero unused rows)
    for (int e = tid; e < WIN * DM; e += 512) {
        int i = e >> 9, m = e & 511;
        mrow[i][m] = (i < wlen) ? mem[((size_t)b * T + wstart + i) * DM + m] : 0.f;
    }

    // conv location features
    if (tid < WIN * F) {
        int i = tid >> 5, f = tid & 31;
        if (i < wlen) {
            int t = wstart + i;
            float acc = cb[f];
            for (int k = 0; k < KK; ++k) {
                int tt = t + k - 15;
                float x = (tt >= 0 && tt < T) ? pa[(size_t)b * T + tt] : 0.f;
                acc += x * ck[k * F + f];
            }
            fsh[i][f] = acc;
        } else if (i < WIN) {
            fsh[i][f] = 0.f;
        }
    }
    __syncthreads();

    // pq partials: (j=tid>>7, d=tid&127), each sums 256 of 1024 k
    {
        int d = tid & 127, j = tid >> 7;
        int k0 = j * 256;
        float acc = 0.f;
        for (int k = 0; k < 256; ++k) acc += qs[k0 + k] * Wq[(size_t)(k0 + k) * D + d];
        pqpart[j][d] = acc;
    }
    __syncthreads();
    if (tid < D)
        pqs[tid] = pqpart[0][tid] + pqpart[1][tid] + pqpart[2][tid] + pqpart[3][tid] + sb[tid];

    if (wlen > 0) {
        // m-split energies: wave w owns rows [w*64, w*64+64), all WIN positions
        const float2* Wm2 = (const float2*)Wm;
        float2 acc[WIN];
        #pragma unroll
        for (int i = 0; i < WIN; ++i) { acc[i].x = 0.f; acc[i].y = 0.f; }
        int m0 = wave * 64;
        for (int mm = 0; mm < 64; ++mm) {
            int m = m0 + mm;
            float2 wrow = Wm2[(size_t)m * 64 + lane];
            #pragma unroll
            for (int i = 0; i < WIN; ++i) {
                float a = mrow[i][m];
                acc[i].x += a * wrow.x;
                acc[i].y += a * wrow.y;
            }
        }
        #pragma unroll
        for (int i = 0; i < WIN; ++i) pacc2[i][wave][lane] = acc[i];
    }
    __syncthreads();

    if (wave < wlen) {
        int i = wave;
        float2 s = {0.f, 0.f};
        #pragma unroll
        for (int w = 0; w < 8; ++w) {
            s.x += pacc2[i][w][lane].x;
            s.y += pacc2[i][w][lane].y;
        }
        const float2* Wl2 = (const float2*)Wloc;
        float p0 = 0.f, p1 = 0.f;
        #pragma unroll
        for (int f = 0; f < F; ++f) {
            float fv = fsh[i][f];
            float2 wv = Wl2[f * 64 + lane];
            p0 += fv * wv.x; p1 += fv * wv.y;
        }
        int c0 = 2 * lane, c1 = c0 + 1;
        float x = sv[c0] * tanhf(s.x + pqs[c0] + p0)
                + sv[c1] * tanhf(s.y + pqs[c1] + p1);
        for (int o = 32; o > 0; o >>= 1) x += __shfl_xor(x, o);
        if (lane == 0) esh[i] = x;
    }
    __syncthreads();

    if (tid == 0) {
        float a[WIN];
        int best = 0;
        if (wlen > 0) {
            float mx = esh[0];
            for (int i = 1; i < wlen; ++i) if (esh[i] > mx) mx = esh[i];
            float s = 0.f;
            for (int i = 0; i < wlen; ++i) { a[i] = expf(esh[i] - mx); s += a[i]; }
            float inv = 1.f / s;
            float ab = -1.f;
            for (int i = 0; i < wlen; ++i) {
                a[i] *= inv;
                if (a[i] > ab) { ab = a[i]; best = i; }
            }
        }
        for (int i = 0; i < 8; ++i) {
            float av = (i < wlen) ? a[i] : 0.f;
            ash[i] = av;
            wa[b * 8 + i] = av;
        }
        meta[b * 4 + 0] = wstart;
        meta[b * 4 + 1] = wlen;
        meta[b * 4 + 2] = (wlen > 0) ? (wstart + best) : 0;
        meta[b * 4 + 3] = 0;
    }
    __syncthreads();

    // window context (non-degenerate only): ctx[m] = sum_i a[i]*mrow[i][m]
    if (wlen > 0) {
        float s = 0.f;
        #pragma unroll
        for (int i = 0; i < WIN; ++i) s += ash[i] * mrow[i][tid];
        ctx[b * DM + tid] = s;
    }
}

// ---------------- K2: outputs + partial-reduce + attention GEMV -------------------
__global__ void __launch_bounds__(256)
K2(const float* __restrict__ pa, const int* __restrict__ pm, const int* __restrict__ ml,
   const float* __restrict__ wa, const int* __restrict__ meta,
   const float* __restrict__ ctx, const float* __restrict__ part,
   const float* __restrict__ Wm, float* __restrict__ out, int mode) {
    int b = blockIdx.x >> 3, c = blockIdx.x & 7;
    int tid = threadIdx.x;                       // 256
    int p = pm[b], L = ml[b];
    bool deg = (p >= L);
    int ws_ = meta[b * 4], wl = meta[b * 4 + 1];

    int t = c * NTB + tid;
    if (tid < NTB) {
        float a;
        if (deg) a = 1.f / (float)T;
        else     a = (t >= ws_ && t < ws_ + wl) ? wa[b * 8 + (t - ws_)] : 0.f;
        out[OUT_ALIGN + b * T + t] = a;
        out[OUT_NEXT + b * T + t] = pa[(size_t)b * T + t] + a;
    }

    if (c == 0) {
        __shared__ float ctxs[DM];
        __shared__ float red[D];
        if (deg && mode == 0) {
            for (int m = tid; m < DM; m += 256) {
                float s = 0.f;
                for (int cc = 0; cc < NCH; ++cc)
                    s += part[((size_t)b * NCH + cc) * DM + m];
                ctxs[m] = s;
            }
        } else {
            for (int m = tid; m < DM; m += 256) ctxs[m] = ctx[b * DM + m];
        }
        __syncthreads();
        int col = tid & 127, half = tid >> 7;
        int mbase = half * 256;
        float acc = 0.f;
        for (int mm = 0; mm < 256; ++mm)
            acc += ctxs[mbase + mm] * Wm[(size_t)(mbase + mm) * D + col];
        if (half == 1) red[col] = acc;
        __syncthreads();
        if (half == 0) out[b * D + col] = acc + red[col];
        if (tid == 0) out[OUT_ARG + b] = (float)meta[b * 4 + 2];
    }
}

extern "C" void kernel_launch(void* const* d_in, const int* in_sizes, int n_in,
                              void* d_out, int out_size, void* d_ws, size_t ws_size,
                              hipStream_t stream) {
    const float* query = (const float*)d_in[0];
    const float* memory = (const float*)d_in[1];
    const float* prev_align = (const float*)d_in[2];
    const int* prev_max = (const int*)d_in[3];
    const int* mem_len = (const int*)d_in[4];
    const float* Wq = (const float*)d_in[5];
    const float* Wm = (const float*)d_in[6];
    const float* ck = (const float*)d_in[7];
    const float* cb = (const float*)d_in[8];
    const float* Wloc = (const float*)d_in[9];
    const float* sv = (const float*)d_in[10];
    const float* sb = (const float*)d_in[11];
    float* out = (float*)d_out;

    float* wsf = (float*)d_ws;
    float* wa = wsf + WA_OFF;
    int* meta = (int*)(wsf + META_OFF);
    float* ctx = wsf + CTX_OFF;
    float* part = wsf + PART_OFF;

    size_t need = (size_t)(PART_OFF + B * NCH * DM) * 4;
    int mode = (ws_size >= need) ? 0 : 1;

    if (mode == 1)  // atomic fallback: ctx must start at zero
        hipMemsetAsync(ctx, 0, B * DM * sizeof(float), stream);

    K1<<<B + B * NCH, 512, 0, stream>>>(query, memory, prev_align, prev_max, mem_len,
                                        Wq, Wm, ck, cb, Wloc, sv, sb,
                                        wa, meta, ctx, part, mode);
    K2<<<B * NB2, 256, 0, stream>>>(prev_align, prev_max, mem_len, wa, meta,
                                    ctx, part, Wm, out, mode);
}